// Round 1
// baseline (963.511 us; speedup 1.0000x reference)
//
#include <hip/hip_runtime.h>
#include <cstdint>

typedef _Float16 half8  __attribute__((ext_vector_type(8)));
typedef _Float16 half4v __attribute__((ext_vector_type(4)));
typedef float    f32x4  __attribute__((ext_vector_type(4)));

#define MFMA_F16(a,b,c) __builtin_amdgcn_mfma_f32_16x16x32_f16(a,b,c,0,0,0)

static constexpr int D = 1024, H = 16, DK = 64, BATCH = 8, NQ = 1024;
static constexpr int NKP = 1040;  // 1024 real keys + 8 memory slots + 8 pad

// ---------------------------------------------------------------------------
// QKV projection: C = A(fp32) @ fp16(W)^T + fp16(bias); A rows are flat (n*8+b).
// Outputs per-head layouts: Q[b][h][n][dk] (pre-scaled 1/8), K/V[b][h][key][dk].
// ---------------------------------------------------------------------------
__global__ __launch_bounds__(256) void gemm_qkv(
    const float* __restrict__ Aq, const float* __restrict__ Ak, const float* __restrict__ Av,
    const float* __restrict__ W, const float* __restrict__ bias,
    _Float16* __restrict__ Qo, _Float16* __restrict__ Ko, _Float16* __restrict__ Vo)
{
  const int z = blockIdx.z;
  const float* __restrict__ A = (z == 0) ? Aq : ((z == 1) ? Ak : Av);
  const int row0 = blockIdx.x * 128;
  const int col0 = blockIdx.y * 128;
  const float* __restrict__ Wz = W + (size_t)z * D * D;

  __shared__ _Float16 As[128 * 40];   // 128 x 32, stride 40 (pad breaks conflicts)
  __shared__ _Float16 Bs[128 * 40];

  const int tid = threadIdx.x;
  const int wv = tid >> 6, lane = tid & 63, c = lane & 15, g = lane >> 4;
  const int ar0 = (wv & 1) * 64, bc0 = (wv >> 1) * 64;

  f32x4 acc[4][4];
#pragma unroll
  for (int i = 0; i < 4; i++)
#pragma unroll
    for (int j = 0; j < 4; j++) acc[i][j] = (f32x4)(0.f);

  for (int kb = 0; kb < D; kb += 32) {
#pragma unroll
    for (int u = 0; u < 2; u++) {
      int id = tid + 256 * u;
      int row = id >> 2, k8 = (id & 3) * 8;
      const float* ap = A + (size_t)(row0 + row) * D + kb + k8;
      float4 f0 = ((const float4*)ap)[0];
      float4 f1 = ((const float4*)ap)[1];
      half8 ha;
      ha[0]=(_Float16)f0.x; ha[1]=(_Float16)f0.y; ha[2]=(_Float16)f0.z; ha[3]=(_Float16)f0.w;
      ha[4]=(_Float16)f1.x; ha[5]=(_Float16)f1.y; ha[6]=(_Float16)f1.z; ha[7]=(_Float16)f1.w;
      *(half8*)&As[row * 40 + k8] = ha;

      const float* wp = Wz + (size_t)(col0 + row) * D + kb + k8;
      float4 g0 = ((const float4*)wp)[0];
      float4 g1 = ((const float4*)wp)[1];
      half8 hb;
      hb[0]=(_Float16)g0.x; hb[1]=(_Float16)g0.y; hb[2]=(_Float16)g0.z; hb[3]=(_Float16)g0.w;
      hb[4]=(_Float16)g1.x; hb[5]=(_Float16)g1.y; hb[6]=(_Float16)g1.z; hb[7]=(_Float16)g1.w;
      *(half8*)&Bs[row * 40 + k8] = hb;
    }
    __syncthreads();
    half8 af[4], bf[4];
#pragma unroll
    for (int i = 0; i < 4; i++) af[i] = *(const half8*)&As[(ar0 + 16 * i + c) * 40 + 8 * g];
#pragma unroll
    for (int j = 0; j < 4; j++) bf[j] = *(const half8*)&Bs[(bc0 + 16 * j + c) * 40 + 8 * g];
#pragma unroll
    for (int i = 0; i < 4; i++)
#pragma unroll
      for (int j = 0; j < 4; j++) acc[i][j] = MFMA_F16(af[i], bf[j], acc[i][j]);
    __syncthreads();
  }

#pragma unroll
  for (int j = 0; j < 4; j++) {
    int n = col0 + bc0 + 16 * j + c;
    float bb = (float)(_Float16)bias[z * D + n];   // reference casts bias to fp16
    int h_ = n >> 6, dk = n & 63;
#pragma unroll
    for (int i = 0; i < 4; i++) {
#pragma unroll
      for (int r = 0; r < 4; r++) {
        int m = row0 + ar0 + 16 * i + 4 * g + r;
        int b = m & 7, nq = m >> 3;
        float val = acc[i][j][r] + bb;
        if (z == 0)
          Qo[(((size_t)b * H + h_) * NQ + nq) * DK + dk] = (_Float16)(val * 0.125f);
        else if (z == 1)
          Ko[(((size_t)b * H + h_) * NKP + nq) * DK + dk] = (_Float16)val;
        else
          Vo[(((size_t)b * H + h_) * NKP + nq) * DK + dk] = (_Float16)val;
      }
    }
  }
}

// ---------------------------------------------------------------------------
// Memory slots: K rows 1024..1031 = 32*m_k, V rows = sqrt(8)*m_v; rows 1032..1039 = 0.
// ---------------------------------------------------------------------------
__global__ __launch_bounds__(256) void fill_slots(
    const float* __restrict__ mk, const float* __restrict__ mv,
    _Float16* __restrict__ Ko, _Float16* __restrict__ Vo)
{
  int idx = blockIdx.x * 256 + threadIdx.x;   // 262144 total
  int which = idx >> 17;
  int e = idx & 131071;
  int dk = e & 63, r = (e >> 6) & 15, h = (e >> 10) & 15, b = (e >> 14) & 7;
  float val = 0.f;
  if (r < 8) {
    int src = r * D + h * DK + dk;
    val = which ? 2.8284271247461903f * mv[src] : 32.f * mk[src];
  }
  _Float16* dst = which ? Vo : Ko;
  dst[(((size_t)b * H + h) * NKP + 1024 + r) * DK + dk] = (_Float16)val;
}

// ---------------------------------------------------------------------------
// Fused attention: per (b,h), Q-tile 64. S^T = K*Q'^T + mask (mask float4 loads
// ARE the accumulator init). No max-subtraction (logits bounded << 88).
// P -> LDS (b64 writes), O += P*V via MFMA with V transposed in LDS.
// ---------------------------------------------------------------------------
__global__ __launch_bounds__(256) void attn(
    const _Float16* __restrict__ Qg, const _Float16* __restrict__ Kg,
    const _Float16* __restrict__ Vg, const float* __restrict__ mask,
    _Float16* __restrict__ Hid)
{
  const int qt = blockIdx.x;        // 0..15
  const int bh = blockIdx.y;        // 0..127 == b*16+h
  const int b = bh >> 4, h = bh & 15;
  const int tid = threadIdx.x;
  const int wv = tid >> 6, lane = tid & 63, c = lane & 15, g = lane >> 4;

  __shared__ _Float16 Qs[64 * 72];
  __shared__ _Float16 Ks[64 * 72];
  __shared__ _Float16 Vt[64 * 72];  // transposed: [dv][key]
  __shared__ _Float16 Ps[64 * 72];  // [q][key], rows wv*16.. are wave-private

  const _Float16* qbase = Qg + ((size_t)bh * NQ + qt * 64) * DK;
#pragma unroll
  for (int u = 0; u < 2; u++) {
    int id = tid + 256 * u;
    int row = id >> 3, m8 = (id & 7) * 8;
    *(int4*)&Qs[row * 72 + m8] = *(const int4*)(qbase + row * DK + m8);
  }
  __syncthreads();
  const int qrow = (wv * 16 + c) * 72;
  half8 qf0 = *(const half8*)&Qs[qrow + 8 * g];
  half8 qf1 = *(const half8*)&Qs[qrow + 32 + 8 * g];

  f32x4 oacc[4];
#pragma unroll
  for (int j = 0; j < 4; j++) oacc[j] = (f32x4)(0.f);
  float lpart = 0.f;

  const float* maskbase = mask + ((size_t)bh << 20) + ((size_t)(qt * 64 + wv * 16 + c) << 10);
  const _Float16* kbase_g = Kg + (size_t)bh * NKP * DK;
  const _Float16* vbase_g = Vg + (size_t)bh * NKP * DK;

  for (int ci = 0; ci < 17; ++ci) {
    const int kb = ci * 64;
    const int nk = (ci < 16) ? 64 : 16;
    __syncthreads();   // prior chunk's MFMA reads of Ks/Vt are done

    f32x4 sinit[4];
    if (ci < 16) {
#pragma unroll
      for (int t = 0; t < 4; t++)
        sinit[t] = *(const f32x4*)(maskbase + kb + 16 * t + 4 * g);
    } else {
      float iv = (g < 2) ? 0.f : -1e30f;   // keys >= 1032 masked out
      sinit[0] = (f32x4){iv, iv, iv, iv};
    }

    // stage K chunk (row-major, padded)
#pragma unroll
    for (int u = 0; u < 2; u++) {
      int id = tid + 256 * u;
      int row = id >> 3, m8 = (id & 7) * 8;
      if (row < nk)
        *(int4*)&Ks[row * 72 + m8] = *(const int4*)(kbase_g + (size_t)(kb + row) * DK + m8);
    }
    // stage V transposed: each thread handles a key-pair x 8-dv block
    {
      int kp = tid & 31, dvo = (tid >> 5) * 8;
      if (2 * kp < nk) {
        uint4 a4 = *(const uint4*)(vbase_g + (size_t)(kb + 2 * kp) * DK + dvo);
        uint4 b4 = *(const uint4*)(vbase_g + (size_t)(kb + 2 * kp + 1) * DK + dvo);
        uint32_t aw[4] = {a4.x, a4.y, a4.z, a4.w};
        uint32_t bw[4] = {b4.x, b4.y, b4.z, b4.w};
#pragma unroll
        for (int w = 0; w < 4; w++) {
          uint32_t lo = (aw[w] & 0xffffu) | (bw[w] << 16);
          uint32_t hi = (aw[w] >> 16) | (bw[w] & 0xffff0000u);
          *(uint32_t*)&Vt[(dvo + 2 * w) * 72 + 2 * kp] = lo;
          *(uint32_t*)&Vt[(dvo + 2 * w + 1) * 72 + 2 * kp] = hi;
        }
      } else if (nk == 16) {
        // zero-pad keys [16,64) so stale LDS can't poison PV
#pragma unroll
        for (int w = 0; w < 4; w++) {
          *(uint32_t*)&Vt[(dvo + 2 * w) * 72 + 2 * kp] = 0u;
          *(uint32_t*)&Vt[(dvo + 2 * w + 1) * 72 + 2 * kp] = 0u;
        }
      }
    }
    __syncthreads();

    const int ntile = nk >> 4;
    for (int t = 0; t < ntile; ++t) {
      f32x4 s = sinit[t];
      half8 kf0 = *(const half8*)&Ks[(16 * t + c) * 72 + 8 * g];
      half8 kf1 = *(const half8*)&Ks[(16 * t + c) * 72 + 32 + 8 * g];
      s = MFMA_F16(kf0, qf0, s);
      s = MFMA_F16(kf1, qf1, s);
      f32x4 p;
      p[0] = __expf(s[0]); p[1] = __expf(s[1]); p[2] = __expf(s[2]); p[3] = __expf(s[3]);
      lpart += p[0] + p[1] + p[2] + p[3];
      half4v ph;
      ph[0] = (_Float16)p[0]; ph[1] = (_Float16)p[1];
      ph[2] = (_Float16)p[2]; ph[3] = (_Float16)p[3];
      *(half4v*)&Ps[qrow + 16 * t + 4 * g] = ph;   // P[q][key], 4 consecutive keys
    }
    if (nk == 16) {
      half4v zz = {(_Float16)0, (_Float16)0, (_Float16)0, (_Float16)0};
      *(half4v*)&Ps[qrow + 16 + 4 * g] = zz;       // zero keys 16..31
    }

    const int khalf = (nk == 64) ? 2 : 1;
    for (int kh = 0; kh < khalf; ++kh) {
      half8 pf = *(const half8*)&Ps[qrow + 32 * kh + 8 * g];
#pragma unroll
      for (int j = 0; j < 4; j++) {
        half8 vf = *(const half8*)&Vt[(16 * j + c) * 72 + 32 * kh + 8 * g];
        oacc[j] = MFMA_F16(pf, vf, oacc[j]);
      }
    }
  }

  // finalize: row sums of exp live per-column(q=c); reduce over g groups
  lpart += __shfl_xor(lpart, 16);
  lpart += __shfl_xor(lpart, 32);
  float inv_[4];
#pragma unroll
  for (int r = 0; r < 4; r++) {
    float lq = __shfl(lpart, 4 * g + r);   // lane with c == 4g+r holds l for that q row
    inv_[r] = __builtin_amdgcn_rcpf(lq);
  }
#pragma unroll
  for (int j = 0; j < 4; j++) {
    int col = h * DK + 16 * j + c;
#pragma unroll
    for (int r = 0; r < 4; r++) {
      int q = qt * 64 + wv * 16 + 4 * g + r;
      Hid[((size_t)q * BATCH + b) * D + col] = (_Float16)(oacc[j][r] * inv_[r]);
    }
  }
}

// ---------------------------------------------------------------------------
// Output projection: out = Hid(fp16) @ fp16(out_w)^T + out_b (fp32 out).
// ---------------------------------------------------------------------------
__global__ __launch_bounds__(256) void gemm_out(
    const _Float16* __restrict__ Ah, const float* __restrict__ W,
    const float* __restrict__ bias, float* __restrict__ Out)
{
  const int row0 = blockIdx.x * 128, col0 = blockIdx.y * 128;
  __shared__ _Float16 As[128 * 40];
  __shared__ _Float16 Bs[128 * 40];
  const int tid = threadIdx.x;
  const int wv = tid >> 6, lane = tid & 63, c = lane & 15, g = lane >> 4;
  const int ar0 = (wv & 1) * 64, bc0 = (wv >> 1) * 64;

  f32x4 acc[4][4];
#pragma unroll
  for (int i = 0; i < 4; i++)
#pragma unroll
    for (int j = 0; j < 4; j++) acc[i][j] = (f32x4)(0.f);

  for (int kb = 0; kb < D; kb += 32) {
#pragma unroll
    for (int u = 0; u < 2; u++) {
      int id = tid + 256 * u;
      int row = id >> 2, k8 = (id & 3) * 8;
      *(int4*)&As[row * 40 + k8] =
          *(const int4*)(Ah + (size_t)(row0 + row) * D + kb + k8);
      const float* wp = W + (size_t)(col0 + row) * D + kb + k8;
      float4 g0 = ((const float4*)wp)[0];
      float4 g1 = ((const float4*)wp)[1];
      half8 hb;
      hb[0]=(_Float16)g0.x; hb[1]=(_Float16)g0.y; hb[2]=(_Float16)g0.z; hb[3]=(_Float16)g0.w;
      hb[4]=(_Float16)g1.x; hb[5]=(_Float16)g1.y; hb[6]=(_Float16)g1.z; hb[7]=(_Float16)g1.w;
      *(half8*)&Bs[row * 40 + k8] = hb;
    }
    __syncthreads();
    half8 af[4], bf[4];
#pragma unroll
    for (int i = 0; i < 4; i++) af[i] = *(const half8*)&As[(ar0 + 16 * i + c) * 40 + 8 * g];
#pragma unroll
    for (int j = 0; j < 4; j++) bf[j] = *(const half8*)&Bs[(bc0 + 16 * j + c) * 40 + 8 * g];
#pragma unroll
    for (int i = 0; i < 4; i++)
#pragma unroll
      for (int j = 0; j < 4; j++) acc[i][j] = MFMA_F16(af[i], bf[j], acc[i][j]);
    __syncthreads();
  }

#pragma unroll
  for (int j = 0; j < 4; j++) {
    int n = col0 + bc0 + 16 * j + c;
    float bb = bias[n];   // out_b stays fp32 in the reference
#pragma unroll
    for (int i = 0; i < 4; i++) {
#pragma unroll
      for (int r = 0; r < 4; r++) {
        int m = row0 + ar0 + 16 * i + 4 * g + r;
        Out[(size_t)m * D + n] = acc[i][j][r] + bb;
      }
    }
  }
}

// ---------------------------------------------------------------------------
extern "C" void kernel_launch(void* const* d_in, const int* in_sizes, int n_in,
                              void* d_out, int out_size, void* d_ws, size_t ws_size,
                              hipStream_t stream) {
  const float* queries   = (const float*)d_in[0];
  const float* keys      = (const float*)d_in[1];
  const float* values    = (const float*)d_in[2];
  const float* m_k       = (const float*)d_in[3];
  const float* m_v       = (const float*)d_in[4];
  const float* attn_mask = (const float*)d_in[5];
  const float* in_proj_w = (const float*)d_in[6];
  const float* in_proj_b = (const float*)d_in[7];
  const float* out_w     = (const float*)d_in[8];
  const float* out_b     = (const float*)d_in[9];
  float* out = (float*)d_out;

  _Float16* Qw = (_Float16*)d_ws;                       // 8*16*1024*64
  _Float16* Kw = Qw + (size_t)8 * 16 * 1024 * 64;       // 8*16*1040*64
  _Float16* Vw = Kw + (size_t)8 * 16 * 1040 * 64;       // 8*16*1040*64
  _Float16* Hw = Vw + (size_t)8 * 16 * 1040 * 64;       // 8192*1024

  hipLaunchKernelGGL(gemm_qkv, dim3(64, 8, 3), dim3(256), 0, stream,
                     queries, keys, values, in_proj_w, in_proj_b, Qw, Kw, Vw);
  hipLaunchKernelGGL(fill_slots, dim3(1024), dim3(256), 0, stream, m_k, m_v, Kw, Vw);
  hipLaunchKernelGGL(attn, dim3(16, 128), dim3(256), 0, stream, Qw, Kw, Vw, attn_mask, Hw);
  hipLaunchKernelGGL(gemm_out, dim3(64, 8), dim3(256), 0, stream, Hw, out_w, out_b, out);
}

// Round 2
// 948.621 us; speedup vs baseline: 1.0157x; 1.0157x over previous
//
#include <hip/hip_runtime.h>
#include <cstdint>

typedef _Float16 half8  __attribute__((ext_vector_type(8)));
typedef _Float16 half4v __attribute__((ext_vector_type(4)));
typedef float    f32x4  __attribute__((ext_vector_type(4)));

#define MFMA_F16(a,b,c) __builtin_amdgcn_mfma_f32_16x16x32_f16(a,b,c,0,0,0)

static constexpr int D = 1024, H = 16, DK = 64, BATCH = 8, NQ = 1024;
static constexpr int NKP = 1040;  // 1024 real keys + 8 memory slots + 8 pad

// Async global->LDS, 16B per lane. LDS dest is wave-uniform base + lane*16.
__device__ __forceinline__ void async_copy16(_Float16* lds, const _Float16* g) {
  __builtin_amdgcn_global_load_lds(
      (const __attribute__((address_space(1))) void*)g,
      (__attribute__((address_space(3))) void*)lds, 16, 0, 0);
}

// ---------------------------------------------------------------------------
// One-shot fp32 -> fp16 convert of activations + weights (8 elems/thread).
// Segments: q | k | v (8192*1024 each) | in_proj_w (3M) | out_w (1M).
// ---------------------------------------------------------------------------
__global__ __launch_bounds__(256) void convert_all(
    const float* __restrict__ q, const float* __restrict__ k, const float* __restrict__ v,
    const float* __restrict__ w_in, const float* __restrict__ w_out,
    _Float16* __restrict__ q16, _Float16* __restrict__ k16, _Float16* __restrict__ v16,
    _Float16* __restrict__ win16, _Float16* __restrict__ wout16)
{
  const unsigned NA = 8192u * 1024u;
  const unsigned NW = 3u * 1024u * 1024u;
  unsigned idx = blockIdx.x * 256u + threadIdx.x;
  unsigned e = idx * 8u;
  const float* src;
  _Float16* dst;
  unsigned off;
  if (e < NA)            { src = q;     dst = q16;    off = e; }
  else if (e < 2 * NA)   { src = k;     dst = k16;    off = e - NA; }
  else if (e < 3 * NA)   { src = v;     dst = v16;    off = e - 2 * NA; }
  else if (e < 3 * NA + NW) { src = w_in; dst = win16; off = e - 3 * NA; }
  else                   { src = w_out; dst = wout16; off = e - 3 * NA - NW; }
  float4 f0 = ((const float4*)(src + off))[0];
  float4 f1 = ((const float4*)(src + off))[1];
  half8 h;
  h[0]=(_Float16)f0.x; h[1]=(_Float16)f0.y; h[2]=(_Float16)f0.z; h[3]=(_Float16)f0.w;
  h[4]=(_Float16)f1.x; h[5]=(_Float16)f1.y; h[6]=(_Float16)f1.z; h[7]=(_Float16)f1.w;
  *(half8*)(dst + off) = h;
}

// ---------------------------------------------------------------------------
// QKV projection on fp16 inputs, m97-style global_load_lds staging.
// C = A @ W^T + fp16(bias). Epilogue scatters to per-head Q/K/V layouts.
// ---------------------------------------------------------------------------
__global__ __launch_bounds__(256) void gemm_qkv(
    const _Float16* __restrict__ A16,  // 3 segments of 8192x1024, z-indexed
    const _Float16* __restrict__ W16,  // 3072x1024
    const float* __restrict__ bias,
    _Float16* __restrict__ Qo, _Float16* __restrict__ Ko, _Float16* __restrict__ Vo)
{
  const int z = blockIdx.z;
  const _Float16* __restrict__ A = A16 + (size_t)z * 8192 * 1024;
  const _Float16* __restrict__ Wz = W16 + (size_t)z * D * D;
  const int row0 = blockIdx.x * 128;
  const int col0 = blockIdx.y * 128;

  __shared__ _Float16 As[128 * 32];
  __shared__ _Float16 Bs[128 * 32];

  const int tid = threadIdx.x;
  const int wv = tid >> 6, lane = tid & 63, c = lane & 15, g = lane >> 4;
  const int ar0 = (wv & 1) * 64, bc0 = (wv >> 1) * 64;

  // staging: wave wv covers tile rows [32wv, 32wv+32), lane -> (row, 8k)
  const int srow = 32 * wv + (lane >> 2);
  const int sk8 = (lane & 3) * 8;
  const _Float16* ag = A + (size_t)(row0 + srow) * D + sk8;
  const _Float16* bg = Wz + (size_t)(col0 + srow) * D + sk8;
  _Float16* al = &As[(32 * wv) * 32];
  _Float16* bl = &Bs[(32 * wv) * 32];

  f32x4 acc[4][4];
#pragma unroll
  for (int i = 0; i < 4; i++)
#pragma unroll
    for (int j = 0; j < 4; j++) acc[i][j] = (f32x4)(0.f);

  for (int kb = 0; kb < D; kb += 32) {
    async_copy16(al,           ag + kb);
    async_copy16(al + 16 * 32, ag + kb + (size_t)16 * D);
    async_copy16(bl,           bg + kb);
    async_copy16(bl + 16 * 32, bg + kb + (size_t)16 * D);
    __syncthreads();
    half8 af[4], bf[4];
#pragma unroll
    for (int i = 0; i < 4; i++) af[i] = *(const half8*)&As[(ar0 + 16 * i + c) * 32 + 8 * g];
#pragma unroll
    for (int j = 0; j < 4; j++) bf[j] = *(const half8*)&Bs[(bc0 + 16 * j + c) * 32 + 8 * g];
#pragma unroll
    for (int i = 0; i < 4; i++)
#pragma unroll
      for (int j = 0; j < 4; j++) acc[i][j] = MFMA_F16(af[i], bf[j], acc[i][j]);
    __syncthreads();
  }

#pragma unroll
  for (int j = 0; j < 4; j++) {
    int n = col0 + bc0 + 16 * j + c;
    float bb = (float)(_Float16)bias[z * D + n];   // reference casts bias to fp16
    int h_ = n >> 6, dk = n & 63;
#pragma unroll
    for (int i = 0; i < 4; i++) {
#pragma unroll
      for (int r = 0; r < 4; r++) {
        int m = row0 + ar0 + 16 * i + 4 * g + r;
        int b = m & 7, nq = m >> 3;
        float val = acc[i][j][r] + bb;
        if (z == 0)
          Qo[(((size_t)b * H + h_) * NQ + nq) * DK + dk] = (_Float16)(val * 0.125f);
        else if (z == 1)
          Ko[(((size_t)b * H + h_) * NKP + nq) * DK + dk] = (_Float16)val;
        else
          Vo[(((size_t)b * H + h_) * NKP + nq) * DK + dk] = (_Float16)val;
      }
    }
  }
}

// ---------------------------------------------------------------------------
// Memory slots: K rows 1024..1031 = 32*m_k, V rows = sqrt(8)*m_v; 1032..1039 = 0.
// ---------------------------------------------------------------------------
__global__ __launch_bounds__(256) void fill_slots(
    const float* __restrict__ mk, const float* __restrict__ mv,
    _Float16* __restrict__ Ko, _Float16* __restrict__ Vo)
{
  int idx = blockIdx.x * 256 + threadIdx.x;   // 262144 total
  int which = idx >> 17;
  int e = idx & 131071;
  int dk = e & 63, r = (e >> 6) & 15, h = (e >> 10) & 15, b = (e >> 14) & 7;
  float val = 0.f;
  if (r < 8) {
    int src = r * D + h * DK + dk;
    val = which ? 2.8284271247461903f * mv[src] : 32.f * mk[src];
  }
  _Float16* dst = which ? Vo : Ko;
  dst[(((size_t)b * H + h) * NKP + 1024 + r) * DK + dk] = (_Float16)val;
}

// ---------------------------------------------------------------------------
// Fused attention: per (b,h), Q-tile 64. S^T = K*Q'^T + mask (mask float4 loads
// ARE the accumulator init). No max-subtraction (logits bounded << 88).
// P -> LDS (b64 writes), O += P*V via MFMA with V transposed in LDS.
// ---------------------------------------------------------------------------
__global__ __launch_bounds__(256) void attn(
    const _Float16* __restrict__ Qg, const _Float16* __restrict__ Kg,
    const _Float16* __restrict__ Vg, const float* __restrict__ mask,
    _Float16* __restrict__ Hid)
{
  const int qt = blockIdx.x;        // 0..15
  const int bh = blockIdx.y;        // 0..127 == b*16+h
  const int b = bh >> 4, h = bh & 15;
  const int tid = threadIdx.x;
  const int wv = tid >> 6, lane = tid & 63, c = lane & 15, g = lane >> 4;

  __shared__ _Float16 Qs[64 * 72];
  __shared__ _Float16 Ks[64 * 72];
  __shared__ _Float16 Vt[64 * 72];  // transposed: [dv][key]
  __shared__ _Float16 Ps[64 * 72];  // [q][key], rows wv*16.. are wave-private

  const _Float16* qbase = Qg + ((size_t)bh * NQ + qt * 64) * DK;
#pragma unroll
  for (int u = 0; u < 2; u++) {
    int id = tid + 256 * u;
    int row = id >> 3, m8 = (id & 7) * 8;
    *(int4*)&Qs[row * 72 + m8] = *(const int4*)(qbase + row * DK + m8);
  }
  __syncthreads();
  const int qrow = (wv * 16 + c) * 72;
  half8 qf0 = *(const half8*)&Qs[qrow + 8 * g];
  half8 qf1 = *(const half8*)&Qs[qrow + 32 + 8 * g];

  f32x4 oacc[4];
#pragma unroll
  for (int j = 0; j < 4; j++) oacc[j] = (f32x4)(0.f);
  float lpart = 0.f;

  const float* maskbase = mask + ((size_t)bh << 20) + ((size_t)(qt * 64 + wv * 16 + c) << 10);
  const _Float16* kbase_g = Kg + (size_t)bh * NKP * DK;
  const _Float16* vbase_g = Vg + (size_t)bh * NKP * DK;

  for (int ci = 0; ci < 17; ++ci) {
    const int kb = ci * 64;
    const int nk = (ci < 16) ? 64 : 16;
    __syncthreads();   // prior chunk's MFMA reads of Ks/Vt are done

    f32x4 sinit[4];
    if (ci < 16) {
#pragma unroll
      for (int t = 0; t < 4; t++)
        sinit[t] = *(const f32x4*)(maskbase + kb + 16 * t + 4 * g);
    } else {
      float iv = (g < 2) ? 0.f : -1e30f;   // keys >= 1032 masked out
      sinit[0] = (f32x4){iv, iv, iv, iv};
    }

    // stage K chunk (row-major, padded)
#pragma unroll
    for (int u = 0; u < 2; u++) {
      int id = tid + 256 * u;
      int row = id >> 3, m8 = (id & 7) * 8;
      if (row < nk)
        *(int4*)&Ks[row * 72 + m8] = *(const int4*)(kbase_g + (size_t)(kb + row) * DK + m8);
    }
    // stage V transposed: each thread handles a key-pair x 8-dv block
    {
      int kp = tid & 31, dvo = (tid >> 5) * 8;
      if (2 * kp < nk) {
        uint4 a4 = *(const uint4*)(vbase_g + (size_t)(kb + 2 * kp) * DK + dvo);
        uint4 b4 = *(const uint4*)(vbase_g + (size_t)(kb + 2 * kp + 1) * DK + dvo);
        uint32_t aw[4] = {a4.x, a4.y, a4.z, a4.w};
        uint32_t bw[4] = {b4.x, b4.y, b4.z, b4.w};
#pragma unroll
        for (int w = 0; w < 4; w++) {
          uint32_t lo = (aw[w] & 0xffffu) | (bw[w] << 16);
          uint32_t hi = (aw[w] >> 16) | (bw[w] & 0xffff0000u);
          *(uint32_t*)&Vt[(dvo + 2 * w) * 72 + 2 * kp] = lo;
          *(uint32_t*)&Vt[(dvo + 2 * w + 1) * 72 + 2 * kp] = hi;
        }
      } else if (nk == 16) {
        // zero-pad keys [16,64) so stale LDS can't poison PV
#pragma unroll
        for (int w = 0; w < 4; w++) {
          *(uint32_t*)&Vt[(dvo + 2 * w) * 72 + 2 * kp] = 0u;
          *(uint32_t*)&Vt[(dvo + 2 * w + 1) * 72 + 2 * kp] = 0u;
        }
      }
    }
    __syncthreads();

    const int ntile = nk >> 4;
    for (int t = 0; t < ntile; ++t) {
      f32x4 s = sinit[t];
      half8 kf0 = *(const half8*)&Ks[(16 * t + c) * 72 + 8 * g];
      half8 kf1 = *(const half8*)&Ks[(16 * t + c) * 72 + 32 + 8 * g];
      s = MFMA_F16(kf0, qf0, s);
      s = MFMA_F16(kf1, qf1, s);
      f32x4 p;
      p[0] = __expf(s[0]); p[1] = __expf(s[1]); p[2] = __expf(s[2]); p[3] = __expf(s[3]);
      lpart += p[0] + p[1] + p[2] + p[3];
      half4v ph;
      ph[0] = (_Float16)p[0]; ph[1] = (_Float16)p[1];
      ph[2] = (_Float16)p[2]; ph[3] = (_Float16)p[3];
      *(half4v*)&Ps[qrow + 16 * t + 4 * g] = ph;   // P[q][key], 4 consecutive keys
    }
    if (nk == 16) {
      half4v zz = {(_Float16)0, (_Float16)0, (_Float16)0, (_Float16)0};
      *(half4v*)&Ps[qrow + 16 + 4 * g] = zz;       // zero keys 16..31
    }

    const int khalf = (nk == 64) ? 2 : 1;
    for (int kh = 0; kh < khalf; ++kh) {
      half8 pf = *(const half8*)&Ps[qrow + 32 * kh + 8 * g];
#pragma unroll
      for (int j = 0; j < 4; j++) {
        half8 vf = *(const half8*)&Vt[(16 * j + c) * 72 + 32 * kh + 8 * g];
        oacc[j] = MFMA_F16(pf, vf, oacc[j]);
      }
    }
  }

  // finalize: row sums of exp live per-column(q=c); reduce over g groups
  lpart += __shfl_xor(lpart, 16);
  lpart += __shfl_xor(lpart, 32);
  float inv_[4];
#pragma unroll
  for (int r = 0; r < 4; r++) {
    float lq = __shfl(lpart, 4 * g + r);   // lane with c == 4g+r holds l for that q row
    inv_[r] = __builtin_amdgcn_rcpf(lq);
  }
#pragma unroll
  for (int j = 0; j < 4; j++) {
    int col = h * DK + 16 * j + c;
#pragma unroll
    for (int r = 0; r < 4; r++) {
      int q = qt * 64 + wv * 16 + 4 * g + r;
      Hid[((size_t)q * BATCH + b) * D + col] = (_Float16)(oacc[j][r] * inv_[r]);
    }
  }
}

// ---------------------------------------------------------------------------
// Output projection on fp16: out = Hid @ fp16(out_w)^T + out_b (fp32 out).
// ---------------------------------------------------------------------------
__global__ __launch_bounds__(256) void gemm_out(
    const _Float16* __restrict__ Ah, const _Float16* __restrict__ W16,
    const float* __restrict__ bias, float* __restrict__ Out)
{
  const int row0 = blockIdx.x * 128, col0 = blockIdx.y * 128;
  __shared__ _Float16 As[128 * 32];
  __shared__ _Float16 Bs[128 * 32];
  const int tid = threadIdx.x;
  const int wv = tid >> 6, lane = tid & 63, c = lane & 15, g = lane >> 4;
  const int ar0 = (wv & 1) * 64, bc0 = (wv >> 1) * 64;

  const int srow = 32 * wv + (lane >> 2);
  const int sk8 = (lane & 3) * 8;
  const _Float16* ag = Ah + (size_t)(row0 + srow) * D + sk8;
  const _Float16* bg = W16 + (size_t)(col0 + srow) * D + sk8;
  _Float16* al = &As[(32 * wv) * 32];
  _Float16* bl = &Bs[(32 * wv) * 32];

  f32x4 acc[4][4];
#pragma unroll
  for (int i = 0; i < 4; i++)
#pragma unroll
    for (int j = 0; j < 4; j++) acc[i][j] = (f32x4)(0.f);

  for (int kb = 0; kb < D; kb += 32) {
    async_copy16(al,           ag + kb);
    async_copy16(al + 16 * 32, ag + kb + (size_t)16 * D);
    async_copy16(bl,           bg + kb);
    async_copy16(bl + 16 * 32, bg + kb + (size_t)16 * D);
    __syncthreads();
    half8 af[4], bf[4];
#pragma unroll
    for (int i = 0; i < 4; i++) af[i] = *(const half8*)&As[(ar0 + 16 * i + c) * 32 + 8 * g];
#pragma unroll
    for (int j = 0; j < 4; j++) bf[j] = *(const half8*)&Bs[(bc0 + 16 * j + c) * 32 + 8 * g];
#pragma unroll
    for (int i = 0; i < 4; i++)
#pragma unroll
      for (int j = 0; j < 4; j++) acc[i][j] = MFMA_F16(af[i], bf[j], acc[i][j]);
    __syncthreads();
  }

#pragma unroll
  for (int j = 0; j < 4; j++) {
    int n = col0 + bc0 + 16 * j + c;
    float bb = bias[n];   // out_b stays fp32 in the reference
#pragma unroll
    for (int i = 0; i < 4; i++) {
#pragma unroll
      for (int r = 0; r < 4; r++) {
        int m = row0 + ar0 + 16 * i + 4 * g + r;
        Out[(size_t)m * D + n] = acc[i][j][r] + bb;
      }
    }
  }
}

// ---------------------------------------------------------------------------
extern "C" void kernel_launch(void* const* d_in, const int* in_sizes, int n_in,
                              void* d_out, int out_size, void* d_ws, size_t ws_size,
                              hipStream_t stream) {
  const float* queries   = (const float*)d_in[0];
  const float* keys      = (const float*)d_in[1];
  const float* values    = (const float*)d_in[2];
  const float* m_k       = (const float*)d_in[3];
  const float* m_v       = (const float*)d_in[4];
  const float* attn_mask = (const float*)d_in[5];
  const float* in_proj_w = (const float*)d_in[6];
  const float* in_proj_b = (const float*)d_in[7];
  const float* out_w     = (const float*)d_in[8];
  const float* out_b     = (const float*)d_in[9];
  float* out = (float*)d_out;

  const size_t NA = (size_t)8192 * 1024;
  _Float16* A16  = (_Float16*)d_ws;            // 3*NA  (q16,k16,v16 contiguous)
  _Float16* Win16  = A16 + 3 * NA;             // 3*1024*1024
  _Float16* Wout16 = Win16 + (size_t)3 * 1024 * 1024;  // 1024*1024
  _Float16* Qw = Wout16 + (size_t)1024 * 1024;          // 8*16*1024*64
  _Float16* Kw = Qw + (size_t)8 * 16 * 1024 * 64;       // 8*16*1040*64
  _Float16* Vw = Kw + (size_t)8 * 16 * 1040 * 64;       // 8*16*1040*64
  _Float16* Hw = Vw + (size_t)8 * 16 * 1040 * 64;       // 8192*1024

  hipLaunchKernelGGL(convert_all, dim3(14336), dim3(256), 0, stream,
                     queries, keys, values, in_proj_w, out_w,
                     A16, A16 + NA, A16 + 2 * NA, Win16, Wout16);
  hipLaunchKernelGGL(gemm_qkv, dim3(64, 8, 3), dim3(256), 0, stream,
                     A16, Win16, in_proj_b, Qw, Kw, Vw);
  hipLaunchKernelGGL(fill_slots, dim3(1024), dim3(256), 0, stream, m_k, m_v, Kw, Vw);
  hipLaunchKernelGGL(attn, dim3(16, 128), dim3(256), 0, stream, Qw, Kw, Vw, attn_mask, Hw);
  hipLaunchKernelGGL(gemm_out, dim3(64, 8), dim3(256), 0, stream, Hw, Wout16, out_b, out);
}